// Round 4
// baseline (967.486 us; speedup 1.0000x reference)
//
#include <hip/hip_runtime.h>

#define N0_SRC 495616
#define N0_DST 45056
#define E0 450560
#define N1_DST 4096
#define E1 40960
#define IN_FEATS 256
#define NH 128
#define NC 16

// ===================== CSR build for layer 0 =====================
__global__ void hist_kernel(const int* __restrict__ dst, int* __restrict__ cnt) {
    int e = blockIdx.x * blockDim.x + threadIdx.x;
    if (e < E0) atomicAdd(&cnt[dst[e]], 1);
}

__global__ void __launch_bounds__(1024) scan_kernel(int* __restrict__ cnt,
                                                    int* __restrict__ row_start) {
    __shared__ int partial[1024];
    const int CH = N0_DST / 1024;  // 44
    int t = threadIdx.x;
    int base = t * CH;
    int s = 0;
    for (int j = 0; j < CH; j++) s += cnt[base + j];
    partial[t] = s;
    __syncthreads();
    for (int off = 1; off < 1024; off <<= 1) {
        int v = (t >= off) ? partial[t - off] : 0;
        __syncthreads();
        partial[t] += v;
        __syncthreads();
    }
    int run = partial[t] - s;
    for (int j = 0; j < CH; j++) {
        int c = cnt[base + j];
        row_start[base + j] = run;
        cnt[base + j] = run;
        run += c;
    }
    if (t == 1023) row_start[N0_DST] = run;
}

__global__ void scatter_kernel(const int* __restrict__ dst, int* __restrict__ cursor,
                               int* __restrict__ perm) {
    int e = blockIdx.x * blockDim.x + threadIdx.x;
    if (e < E0) {
        int p = atomicAdd(&cursor[dst[e]], 1);
        perm[p] = e;
    }
}

// ===================== Layer 0 aggregate (gather-only) =====================
// One wave per dst node; float4/lane = 256 feats in registers. 1-deep pipeline
// on both indices and the x row to keep a load in flight during the FMAs.
__global__ void __launch_bounds__(256) agg0_kernel(const float* __restrict__ x,
    const int* __restrict__ src0, const float* __restrict__ w0,
    const int* __restrict__ perm, const int* __restrict__ row_start,
    float* __restrict__ hneigh) {
    int wv = blockIdx.x * 4 + (threadIdx.x >> 6);
    int lane = threadIdx.x & 63;
    if (wv >= N0_DST) return;
    int beg = row_start[wv], end = row_start[wv + 1];
    const float4* x4 = (const float4*)x;
    float4 acc = make_float4(0.f, 0.f, 0.f, 0.f);
    float degs = 0.f;
    if (beg < end) {
        int e = perm[beg];
        int s = src0[e];
        float we = w0[e];
        float4 v = x4[(size_t)s * 64 + lane];
        for (int i = beg; i < end; i++) {
            int s2 = 0; float we2 = 0.f;
            if (i + 1 < end) { int e2 = perm[i + 1]; s2 = src0[e2]; we2 = w0[e2]; }
            float4 vn = v;
            if (i + 1 < end) vn = x4[(size_t)s2 * 64 + lane];
            acc.x += we * v.x; acc.y += we * v.y;
            acc.z += we * v.z; acc.w += we * v.w;
            degs += we;
            v = vn; we = we2;
        }
    }
    float4 xd = x4[(size_t)wv * 64 + lane];
    float inv = 1.0f / (degs + 1.0f);
    float4 r;
    r.x = (acc.x + xd.x) * inv; r.y = (acc.y + xd.y) * inv;
    r.z = (acc.z + xd.z) * inv; r.w = (acc.w + xd.w) * inv;
    ((float4*)hneigh)[(size_t)wv * 64 + lane] = r;
}

// ===================== Layer 0 dense: h0 = relu(hneigh @ Wn0^T + bn0) ========
// 128x128 block tile, K-chunk 32, 8x8 register tile per thread.
// LDS rows padded to 36 floats (144B, 16B-aligned); fragment reads are
// conflict-free: node/col index = ty + 16*i -> bank offset 4 per ty/tx.
__global__ void __launch_bounds__(256) gemm0_v2(const float* __restrict__ A,
    const float* __restrict__ W, const float* __restrict__ bn,
    float* __restrict__ out) {
    __shared__ float At[128][36];
    __shared__ float Wt[128][36];
    const int m0 = blockIdx.x * 128;
    const int tx = threadIdx.x & 15;   // col group
    const int ty = threadIdx.x >> 4;   // node group
    const float4* A4 = (const float4*)A;   // row stride 64 f4
    const float4* W4 = (const float4*)W;   // row stride 64 f4
    float acc[8][8];
#pragma unroll
    for (int i = 0; i < 8; i++)
#pragma unroll
        for (int j = 0; j < 8; j++) acc[i][j] = 0.f;

    for (int kc = 0; kc < IN_FEATS / 32; kc++) {
        int kc4 = kc * 8;
        __syncthreads();
#pragma unroll
        for (int q = 0; q < 4; q++) {
            int idx = threadIdx.x + 256 * q;     // 0..1023
            int r = idx >> 3, c4 = idx & 7;
            float4 v = A4[(size_t)(m0 + r) * 64 + kc4 + c4];
            *(float4*)&At[r][c4 * 4] = v;
            float4 wv = W4[(size_t)r * 64 + kc4 + c4];
            *(float4*)&Wt[r][c4 * 4] = wv;
        }
        __syncthreads();
#pragma unroll
        for (int k4 = 0; k4 < 8; k4++) {
            float4 a[8], w[8];
#pragma unroll
            for (int i = 0; i < 8; i++) a[i] = *(const float4*)&At[ty + 16 * i][k4 * 4];
#pragma unroll
            for (int j = 0; j < 8; j++) w[j] = *(const float4*)&Wt[tx + 16 * j][k4 * 4];
#pragma unroll
            for (int i = 0; i < 8; i++)
#pragma unroll
                for (int j = 0; j < 8; j++) {
                    acc[i][j] += a[i].x * w[j].x;
                    acc[i][j] += a[i].y * w[j].y;
                    acc[i][j] += a[i].z * w[j].z;
                    acc[i][j] += a[i].w * w[j].w;
                }
        }
    }
    float b[8];
#pragma unroll
    for (int j = 0; j < 8; j++) b[j] = bn[tx + 16 * j];
#pragma unroll
    for (int i = 0; i < 8; i++) {
        size_t row = (size_t)(m0 + ty + 16 * i) * NH;
#pragma unroll
        for (int j = 0; j < 8; j++) {
            float v = acc[i][j] + b[j];
            out[row + tx + 16 * j] = v > 0.f ? v : 0.f;
        }
    }
}

// ===================== Layer 1 edge scatter (agg1 is 2 MB -> L2-resident) ====
__global__ void edge1_kernel(const float* __restrict__ h0,
                             const int* __restrict__ src, const int* __restrict__ dst,
                             const float* __restrict__ w,
                             float* __restrict__ agg, float* __restrict__ deg) {
    int t = blockIdx.x * blockDim.x + threadIdx.x;
    int e = t >> 5;
    int lane = t & 31;
    if (e >= E1) return;
    int s = src[e], d = dst[e];
    float we = w[e];
    float4 v = ((const float4*)(h0 + (size_t)s * NH))[lane];
    float* ad = agg + (size_t)d * NH + lane * 4;
    unsafeAtomicAdd(ad + 0, v.x * we);
    unsafeAtomicAdd(ad + 1, v.y * we);
    unsafeAtomicAdd(ad + 2, v.z * we);
    unsafeAtomicAdd(ad + 3, v.w * we);
    if (lane == 0) unsafeAtomicAdd(deg + d, we);
}

// ===================== Layer 1 dense (norm folded into A-staging) ============
__global__ void __launch_bounds__(256) gemm1_v2(const float* __restrict__ agg,
    const float* __restrict__ h0, const float* __restrict__ deg,
    const float* __restrict__ W, const float* __restrict__ bn,
    float* __restrict__ out) {
    __shared__ float At[128][36];
    __shared__ float Wt[128][36];
    const int m0 = blockIdx.x * 128;
    const int tx = threadIdx.x & 15;
    const int ty = threadIdx.x >> 4;
    const float4* G4 = (const float4*)agg;  // row stride 32 f4
    const float4* H4 = (const float4*)h0;   // row stride 32 f4
    const float4* W4 = (const float4*)W;    // row stride 32 f4
    float acc[8][8];
#pragma unroll
    for (int i = 0; i < 8; i++)
#pragma unroll
        for (int j = 0; j < 8; j++) acc[i][j] = 0.f;

    for (int kc = 0; kc < NH / 32; kc++) {
        int kc4 = kc * 8;
        __syncthreads();
#pragma unroll
        for (int q = 0; q < 4; q++) {
            int idx = threadIdx.x + 256 * q;
            int r = idx >> 3, c4 = idx & 7;
            int m = m0 + r;
            float4 g = G4[(size_t)m * 32 + kc4 + c4];
            float4 h = H4[(size_t)m * 32 + kc4 + c4];
            float inv = 1.0f / (deg[m] + 1.0f);
            float4 v;
            v.x = (g.x + h.x) * inv; v.y = (g.y + h.y) * inv;
            v.z = (g.z + h.z) * inv; v.w = (g.w + h.w) * inv;
            *(float4*)&At[r][c4 * 4] = v;
            float4 wv = W4[(size_t)r * 32 + kc4 + c4];
            *(float4*)&Wt[r][c4 * 4] = wv;
        }
        __syncthreads();
#pragma unroll
        for (int k4 = 0; k4 < 8; k4++) {
            float4 a[8], w[8];
#pragma unroll
            for (int i = 0; i < 8; i++) a[i] = *(const float4*)&At[ty + 16 * i][k4 * 4];
#pragma unroll
            for (int j = 0; j < 8; j++) w[j] = *(const float4*)&Wt[tx + 16 * j][k4 * 4];
#pragma unroll
            for (int i = 0; i < 8; i++)
#pragma unroll
                for (int j = 0; j < 8; j++) {
                    acc[i][j] += a[i].x * w[j].x;
                    acc[i][j] += a[i].y * w[j].y;
                    acc[i][j] += a[i].z * w[j].z;
                    acc[i][j] += a[i].w * w[j].w;
                }
        }
    }
    float b[8];
#pragma unroll
    for (int j = 0; j < 8; j++) b[j] = bn[tx + 16 * j];
#pragma unroll
    for (int i = 0; i < 8; i++) {
        size_t row = (size_t)(m0 + ty + 16 * i) * NH;
#pragma unroll
        for (int j = 0; j < 8; j++) {
            float v = acc[i][j] + b[j];
            out[row + tx + 16 * j] = v > 0.f ? v : 0.f;
        }
    }
}

// ===================== Final FC =============================================
__global__ void fc_kernel(const float* __restrict__ h1, const float* __restrict__ Wfc,
                          const float* __restrict__ bfc, float* __restrict__ out) {
    int t = blockIdx.x * blockDim.x + threadIdx.x;
    int m = t >> 4, c = t & 15;
    if (m >= N1_DST) return;
    const float* hr = h1 + (size_t)m * NH;
    const float* wr = Wfc + (size_t)c * NH;
    float acc = 0.f;
    for (int k = 0; k < NH; k++) acc += hr[k] * wr[k];
    out[t] = acc + bfc[c];
}

extern "C" void kernel_launch(void* const* d_in, const int* in_sizes, int n_in,
                              void* d_out, int out_size, void* d_ws, size_t ws_size,
                              hipStream_t stream) {
    const float* x   = (const float*)d_in[0];
    const int* src0  = (const int*)d_in[1];
    const int* dst0  = (const int*)d_in[2];
    const float* w0  = (const float*)d_in[3];
    const int* src1  = (const int*)d_in[4];
    const int* dst1  = (const int*)d_in[5];
    const float* w1  = (const float*)d_in[6];
    const float* Wn0 = (const float*)d_in[7];
    const float* bn0 = (const float*)d_in[8];
    const float* Wn1 = (const float*)d_in[9];
    const float* bn1 = (const float*)d_in[10];
    const float* Wfc = (const float*)d_in[11];
    const float* bfc = (const float*)d_in[12];
    float* out = (float*)d_out;

    float* ws = (float*)d_ws;
    float* agg1      = ws;                           // 524288
    float* deg1      = agg1 + (size_t)N1_DST * NH;   // 4096
    int*   cnt       = (int*)(deg1 + N1_DST);        // 45056 (becomes cursor)
    int*   row_start = cnt + N0_DST;                 // 45057
    int*   perm      = row_start + N0_DST + 1;       // 450560
    float* hneigh    = (float*)(perm + E0);          // 11534336
    float* h0        = hneigh + (size_t)N0_DST * IN_FEATS; // 5767168
    float* h1        = (float*)cnt;                  // reuses cnt/row_start/perm

    size_t zero_floats = (size_t)N1_DST * NH + N1_DST + N0_DST;
    hipMemsetAsync(d_ws, 0, zero_floats * sizeof(float), stream);

    // CSR build for layer 0
    hist_kernel<<<(E0 + 255) / 256, 256, 0, stream>>>(dst0, cnt);
    scan_kernel<<<1, 1024, 0, stream>>>(cnt, row_start);
    scatter_kernel<<<(E0 + 255) / 256, 256, 0, stream>>>(dst0, cnt, perm);

    // layer 0
    agg0_kernel<<<(N0_DST + 3) / 4, 256, 0, stream>>>(x, src0, w0, perm, row_start, hneigh);
    gemm0_v2<<<N0_DST / 128, 256, 0, stream>>>(hneigh, Wn0, bn0, h0);

    // layer 1
    edge1_kernel<<<(E1 * 32) / 256, 256, 0, stream>>>(h0, src1, dst1, w1, agg1, deg1);
    gemm1_v2<<<N1_DST / 128, 256, 0, stream>>>(agg1, h0, deg1, Wn1, bn1, h1);

    // fc
    fc_kernel<<<(N1_DST * NC) / 256, 256, 0, stream>>>(h1, Wfc, bfc, out);
}